// Round 4
// baseline (507.544 us; speedup 1.0000x reference)
//
#include <hip/hip_runtime.h>
#include <math.h>

constexpr int T_TOK = 16384;
constexpr int HDIM  = 2048;
constexpr int NEXP  = 64;
constexpr int TPB   = 64;            // tokens per block
constexpr int NWAVE = 16;
constexpr int KPW   = HDIM / NWAVE;  // 128 k per wave
constexpr int KSTEP = 32;
constexpr int NKS   = KPW / KSTEP;   // 4 k-steps

typedef __attribute__((ext_vector_type(8))) short v8s;   // 8 bf16 (4 VGPRs)
typedef __attribute__((ext_vector_type(4))) float v4f;   // 4 fp32 acc

#define MFMA_BF16 __builtin_amdgcn_mfma_f32_16x16x32_bf16

// Truncation split: x = h + m + l exactly to ~24 mantissa bits.
static __device__ __forceinline__ void split3(float x, unsigned short& h,
                                              unsigned short& m, unsigned short& l)
{
    unsigned u0 = __float_as_uint(x);
    h = (unsigned short)(u0 >> 16);
    float r1 = x - __uint_as_float(u0 & 0xFFFF0000u);     // exact
    unsigned u1 = __float_as_uint(r1);
    m = (unsigned short)(u1 >> 16);
    float r2 = r1 - __uint_as_float(u1 & 0xFFFF0000u);    // exact
    l = (unsigned short)(__float_as_uint(r2) >> 16);
}

static __device__ __forceinline__ void frag3(const float4& x0, const float4& x1,
                                             v8s& h, v8s& m, v8s& l)
{
    unsigned short sh, sm, sl;
    split3(x0.x, sh, sm, sl); h[0]=(short)sh; m[0]=(short)sm; l[0]=(short)sl;
    split3(x0.y, sh, sm, sl); h[1]=(short)sh; m[1]=(short)sm; l[1]=(short)sl;
    split3(x0.z, sh, sm, sl); h[2]=(short)sh; m[2]=(short)sm; l[2]=(short)sl;
    split3(x0.w, sh, sm, sl); h[3]=(short)sh; m[3]=(short)sm; l[3]=(short)sl;
    split3(x1.x, sh, sm, sl); h[4]=(short)sh; m[4]=(short)sm; l[4]=(short)sl;
    split3(x1.y, sh, sm, sl); h[5]=(short)sh; m[5]=(short)sm; l[5]=(short)sl;
    split3(x1.z, sh, sm, sl); h[6]=(short)sh; m[6]=(short)sm; l[6]=(short)sl;
    split3(x1.w, sh, sm, sl); h[7]=(short)sh; m[7]=(short)sm; l[7]=(short)sl;
}

// swizzled expert column for the LDS reduction buffer (breaks 4-way write conflicts)
static __device__ __forceinline__ int swz_e(int tok, int e) {
    return e ^ (((tok >> 2) & 1) << 4);
}

__global__ __launch_bounds__(1024, 4)
void moe_router_mfma(const float* __restrict__ X,
                     const float* __restrict__ Wg,
                     const float* __restrict__ Bg,
                     float* __restrict__ out)
{
    __shared__ float red[4][TPB][NEXP];    // 64 KiB, epilogue only

    const int tid  = threadIdx.x;
    const int lane = tid & 63;
    const int wv   = tid >> 6;             // wave id = k-slice (0..15)
    const int r16  = lane & 15;
    const int q    = lane >> 4;            // quad id (k-chunk selector)
    const int tok0 = blockIdx.x * TPB;

    // A: lane reads X[tok0 + 16*mt + r16][wv*128 + ks*32 + q*8 .. +7]
    const float* pA = X  + (size_t)(tok0 + r16) * HDIM + wv * KPW + q * 8;
    // B: lane reads W[16*nt + r16][same k window]
    const float* pB = Wg + (size_t)r16 * HDIM + wv * KPW + q * 8;

    v4f acc[4][4];
#pragma unroll
    for (int mt = 0; mt < 4; ++mt)
#pragma unroll
        for (int nt = 0; nt < 4; ++nt)
            acc[mt][nt] = (v4f){0.f, 0.f, 0.f, 0.f};

    float4 a0[4], a1[4], b0[4], b1[4];
#pragma unroll
    for (int mt = 0; mt < 4; ++mt) {
        const float* p = pA + (size_t)mt * 16 * HDIM;
        a0[mt] = *(const float4*)p;
        a1[mt] = *(const float4*)(p + 4);
    }
#pragma unroll
    for (int nt = 0; nt < 4; ++nt) {
        const float* p = pB + (size_t)nt * 16 * HDIM;
        b0[nt] = *(const float4*)p;
        b1[nt] = *(const float4*)(p + 4);
    }

    for (int ks = 0; ks < NKS; ++ks) {
        // ---- split current fp32 buffers into bf16 frag triples
        v8s Ah[4], Am[4], Al[4], Bh[4], Bm[4], Bl[4];
#pragma unroll
        for (int mt = 0; mt < 4; ++mt) frag3(a0[mt], a1[mt], Ah[mt], Am[mt], Al[mt]);
#pragma unroll
        for (int nt = 0; nt < 4; ++nt) frag3(b0[nt], b1[nt], Bh[nt], Bm[nt], Bl[nt]);

        // ---- prefetch next k-step (overlaps with the MFMA block below)
        if (ks < NKS - 1) {
            const int off = (ks + 1) * KSTEP;
#pragma unroll
            for (int mt = 0; mt < 4; ++mt) {
                const float* p = pA + (size_t)mt * 16 * HDIM + off;
                a0[mt] = *(const float4*)p;
                a1[mt] = *(const float4*)(p + 4);
            }
#pragma unroll
            for (int nt = 0; nt < 4; ++nt) {
                const float* p = pB + (size_t)nt * 16 * HDIM + off;
                b0[nt] = *(const float4*)p;
                b1[nt] = *(const float4*)(p + 4);
            }
        }

        // ---- 6-product split GEMM: hh + hm + mh + hl + lh + mm
#pragma unroll
        for (int mt = 0; mt < 4; ++mt)
#pragma unroll
            for (int nt = 0; nt < 4; ++nt) {
                v4f a = acc[mt][nt];
                a = MFMA_BF16(Ah[mt], Bh[nt], a, 0, 0, 0);
                a = MFMA_BF16(Ah[mt], Bm[nt], a, 0, 0, 0);
                a = MFMA_BF16(Am[mt], Bh[nt], a, 0, 0, 0);
                a = MFMA_BF16(Ah[mt], Bl[nt], a, 0, 0, 0);
                a = MFMA_BF16(Al[mt], Bh[nt], a, 0, 0, 0);
                a = MFMA_BF16(Am[mt], Bm[nt], a, 0, 0, 0);
                acc[mt][nt] = a;
            }
    }

    // ---- cross-wave K reduction: 4 slots, 4 phases (16 waves)
    // C/D layout: col(expert-local) = lane&15, row(token-local) = q*4 + r
    if (wv < 4) {
#pragma unroll
        for (int mt = 0; mt < 4; ++mt)
#pragma unroll
            for (int nt = 0; nt < 4; ++nt)
#pragma unroll
                for (int r = 0; r < 4; ++r) {
                    int tok = 16 * mt + q * 4 + r;
                    int e   = 16 * nt + r16;
                    red[wv][tok][swz_e(tok, e)] = acc[mt][nt][r];
                }
    }
    __syncthreads();
#pragma unroll
    for (int ph = 1; ph < 4; ++ph) {
        if (wv >= 4 * ph && wv < 4 * (ph + 1)) {
#pragma unroll
            for (int mt = 0; mt < 4; ++mt)
#pragma unroll
                for (int nt = 0; nt < 4; ++nt)
#pragma unroll
                    for (int r = 0; r < 4; ++r) {
                        int tok = 16 * mt + q * 4 + r;
                        int e   = 16 * nt + r16;
                        red[wv - 4 * ph][tok][swz_e(tok, e)] += acc[mt][nt][r];
                    }
        }
        __syncthreads();
    }

    // ---- epilogue: 4 tokens/wave on lanes 0..3 (64 tokens total)
    if (lane < 4) {
        const int tk = wv * 4 + lane;
        const int t  = tok0 + tk;
        float lg[NEXP];
#pragma unroll
        for (int e = 0; e < NEXP; ++e) {
            int es = swz_e(tk, e);
            lg[e] = ((red[0][tk][es] + red[1][tk][es]) +
                     (red[2][tk][es] + red[3][tk][es])) + Bg[e];
        }
        float* outL = out + (size_t)t * NEXP;
#pragma unroll
        for (int e = 0; e < NEXP; e += 4) {
            float4 v = make_float4(lg[e], lg[e+1], lg[e+2], lg[e+3]);
            *(float4*)(outL + e) = v;
        }
        float mx = lg[0];
#pragma unroll
        for (int e = 1; e < NEXP; ++e) mx = fmaxf(mx, lg[e]);
        float S = 0.f;
#pragma unroll
        for (int e = 0; e < NEXP; ++e) { lg[e] = expf(lg[e] - mx); S += lg[e]; }
#pragma unroll
        for (int e = 0; e < NEXP; ++e) lg[e] = lg[e] / S;

        float v1 = lg[0]; int i1 = 0;
        float v2 = -1.0f; int i2 = 0;
#pragma unroll
        for (int e = 1; e < NEXP; ++e) {
            float rv = lg[e];
            bool g1 = rv > v1;
            bool g2 = rv > v2;
            float nv2 = g1 ? v1 : (g2 ? rv : v2);
            int   ni2 = g1 ? i1 : (g2 ? e  : i2);
            v2 = nv2; i2 = ni2;
            v1 = g1 ? rv : v1;
            i1 = g1 ? e  : i1;
        }
        float den = v1 + v2;
        float w1 = v1 / den, w2 = v2 / den;

        float* outW = out + (size_t)T_TOK * NEXP;
        float* outS = outW + (size_t)T_TOK * 2;
        float* outM = outS + (size_t)T_TOK * 2;
        outW[2*t+0] = w1;        outW[2*t+1] = w2;
        outS[2*t+0] = (float)i1; outS[2*t+1] = (float)i2;

        float* mrow = outM + (size_t)t * 2 * NEXP;
#pragma unroll
        for (int e = 0; e < NEXP; e += 4) {
            float4 a = make_float4(e+0==i1?1.f:0.f, e+1==i1?1.f:0.f,
                                   e+2==i1?1.f:0.f, e+3==i1?1.f:0.f);
            *(float4*)(mrow + e) = a;
            float4 b = make_float4(e+0==i2?1.f:0.f, e+1==i2?1.f:0.f,
                                   e+2==i2?1.f:0.f, e+3==i2?1.f:0.f);
            *(float4*)(mrow + NEXP + e) = b;
        }
    }
}

extern "C" void kernel_launch(void* const* d_in, const int* in_sizes, int n_in,
                              void* d_out, int out_size, void* d_ws, size_t ws_size,
                              hipStream_t stream)
{
    const float* X = (const float*)d_in[0];
    const float* W = (const float*)d_in[1];
    const float* B = (const float*)d_in[2];
    float* out     = (float*)d_out;

    dim3 grid(T_TOK / TPB);   // 256 blocks, 1 per CU
    dim3 block(1024);         // 16 waves -> 4 waves/SIMD
    hipLaunchKernelGGL(moe_router_mfma, grid, block, 0, stream, X, W, B, out);
}

// Round 5
// 260.580 us; speedup vs baseline: 1.9477x; 1.9477x over previous
//
#include <hip/hip_runtime.h>
#include <math.h>

constexpr int T_TOK = 16384;
constexpr int HDIM  = 2048;
constexpr int NEXP  = 64;
constexpr int TPB   = 32;            // tokens per block
constexpr int NWAVE = 8;
constexpr int KPW   = HDIM / NWAVE;  // 256 k per wave
constexpr int KSTEP = 32;
constexpr int NKS   = KPW / KSTEP;   // 8 k-steps
constexpr int WPLANE = NEXP * HDIM;  // 131072 ushorts per split plane

typedef __attribute__((ext_vector_type(8))) short v8s;   // 8 bf16 (4 VGPRs)
typedef __attribute__((ext_vector_type(4))) float v4f;   // 4 fp32 acc

#define MFMA_BF16 __builtin_amdgcn_mfma_f32_16x16x32_bf16

// Truncation split: x = h + m + l exactly to ~24 mantissa bits.
static __device__ __forceinline__ void split3(float x, unsigned short& h,
                                              unsigned short& m, unsigned short& l)
{
    unsigned u0 = __float_as_uint(x);
    h = (unsigned short)(u0 >> 16);
    float r1 = x - __uint_as_float(u0 & 0xFFFF0000u);     // exact
    unsigned u1 = __float_as_uint(r1);
    m = (unsigned short)(u1 >> 16);
    float r2 = r1 - __uint_as_float(u1 & 0xFFFF0000u);    // exact
    l = (unsigned short)(__float_as_uint(r2) >> 16);
}

static __device__ __forceinline__ void frag3(const float4& x0, const float4& x1,
                                             v8s& h, v8s& m, v8s& l)
{
    unsigned short sh, sm, sl;
    split3(x0.x, sh, sm, sl); h[0]=(short)sh; m[0]=(short)sm; l[0]=(short)sl;
    split3(x0.y, sh, sm, sl); h[1]=(short)sh; m[1]=(short)sm; l[1]=(short)sl;
    split3(x0.z, sh, sm, sl); h[2]=(short)sh; m[2]=(short)sm; l[2]=(short)sl;
    split3(x0.w, sh, sm, sl); h[3]=(short)sh; m[3]=(short)sm; l[3]=(short)sl;
    split3(x1.x, sh, sm, sl); h[4]=(short)sh; m[4]=(short)sm; l[4]=(short)sl;
    split3(x1.y, sh, sm, sl); h[5]=(short)sh; m[5]=(short)sm; l[5]=(short)sl;
    split3(x1.z, sh, sm, sl); h[6]=(short)sh; m[6]=(short)sm; l[6]=(short)sl;
    split3(x1.w, sh, sm, sl); h[7]=(short)sh; m[7]=(short)sm; l[7]=(short)sl;
}

static __device__ __forceinline__ int swz_e(int tok, int e) {
    return e ^ (((tok >> 2) & 1) << 4);
}

// ---- pass 1: split W into three bf16 planes in d_ws (h | m | l)
__global__ __launch_bounds__(256)
void split_w_kernel(const float* __restrict__ W, unsigned short* __restrict__ ws)
{
    int i = blockIdx.x * 256 + threadIdx.x;        // float4 index, 32768 total
    float4 v = ((const float4*)W)[i];
    ushort4 h, m, l;
    split3(v.x, h.x, m.x, l.x);
    split3(v.y, h.y, m.y, l.y);
    split3(v.z, h.z, m.z, l.z);
    split3(v.w, h.w, m.w, l.w);
    ((ushort4*)(ws           ))[i] = h;
    ((ushort4*)(ws + WPLANE  ))[i] = m;
    ((ushort4*)(ws + 2*WPLANE))[i] = l;
}

// ---- pass 2: MFMA router. 512 blocks x 32 tokens; 8 waves k-split 256 each.
__global__ __launch_bounds__(512, 2)
void moe_router_mfma(const float* __restrict__ X,
                     const unsigned short* __restrict__ Ws,
                     const float* __restrict__ Bg,
                     float* __restrict__ out)
{
    __shared__ float red[4][TPB][NEXP];    // 32 KiB -> 2 blocks/CU fit in 160 KiB

    const int tid  = threadIdx.x;
    const int lane = tid & 63;
    const int wv   = tid >> 6;             // wave id = k-slice (0..7)
    const int r16  = lane & 15;
    const int q    = lane >> 4;            // quad id (k-chunk selector)
    const int tok0 = blockIdx.x * TPB;

    // A: lane reads X[tok0 + 16*mt + r16][wv*256 + ks*32 + q*8 .. +7]
    const float* pA = X + (size_t)(tok0 + r16) * HDIM + wv * KPW + q * 8;
    // B: pre-split bf16 planes; expert row r16 within n-tile nt
    const unsigned short* pBh = Ws + (size_t)r16 * HDIM + wv * KPW + q * 8;

    v4f acc[2][4];
#pragma unroll
    for (int mt = 0; mt < 2; ++mt)
#pragma unroll
        for (int nt = 0; nt < 4; ++nt)
            acc[mt][nt] = (v4f){0.f, 0.f, 0.f, 0.f};

    float4 a0[2], a1[2];
#pragma unroll
    for (int mt = 0; mt < 2; ++mt) {
        const float* p = pA + (size_t)mt * 16 * HDIM;
        a0[mt] = *(const float4*)p;
        a1[mt] = *(const float4*)(p + 4);
    }

    for (int ks = 0; ks < NKS; ++ks) {
        // ---- split current A buffers into bf16 frag triples
        v8s Ah[2], Am[2], Al[2];
#pragma unroll
        for (int mt = 0; mt < 2; ++mt) frag3(a0[mt], a1[mt], Ah[mt], Am[mt], Al[mt]);

        // ---- prefetch next k-step's A (fp32)
        if (ks < NKS - 1) {
            const int off = (ks + 1) * KSTEP;
#pragma unroll
            for (int mt = 0; mt < 2; ++mt) {
                const float* p = pA + (size_t)mt * 16 * HDIM + off;
                a0[mt] = *(const float4*)p;
                a1[mt] = *(const float4*)(p + 4);
            }
        }

        // ---- B frags: double-buffered over nt, loaded straight as bf16
        const unsigned short* pB = pBh + ks * KSTEP;
        v8s Bh[2], Bm[2], Bl[2];
        Bh[0] = *(const v8s*)(pB);
        Bm[0] = *(const v8s*)(pB + WPLANE);
        Bl[0] = *(const v8s*)(pB + 2*WPLANE);

#pragma unroll
        for (int nt = 0; nt < 4; ++nt) {
            const int c = nt & 1, n2 = c ^ 1;
            if (nt < 3) {
                const unsigned short* pn = pB + (size_t)(nt + 1) * 16 * HDIM;
                Bh[n2] = *(const v8s*)(pn);
                Bm[n2] = *(const v8s*)(pn + WPLANE);
                Bl[n2] = *(const v8s*)(pn + 2*WPLANE);
            }
#pragma unroll
            for (int mt = 0; mt < 2; ++mt) {
                v4f a = acc[mt][nt];
                a = MFMA_BF16(Ah[mt], Bh[c], a, 0, 0, 0);
                a = MFMA_BF16(Ah[mt], Bm[c], a, 0, 0, 0);
                a = MFMA_BF16(Am[mt], Bh[c], a, 0, 0, 0);
                a = MFMA_BF16(Ah[mt], Bl[c], a, 0, 0, 0);
                a = MFMA_BF16(Al[mt], Bh[c], a, 0, 0, 0);
                a = MFMA_BF16(Am[mt], Bm[c], a, 0, 0, 0);
                acc[mt][nt] = a;
            }
        }
    }

    // ---- cross-wave K reduction: 4 slots, 2 phases
    // C/D layout: col(expert-local) = lane&15, row(token-local) = q*4 + r
    if (wv < 4) {
#pragma unroll
        for (int mt = 0; mt < 2; ++mt)
#pragma unroll
            for (int nt = 0; nt < 4; ++nt)
#pragma unroll
                for (int r = 0; r < 4; ++r) {
                    int tok = 16 * mt + q * 4 + r;
                    int e   = 16 * nt + r16;
                    red[wv][tok][swz_e(tok, e)] = acc[mt][nt][r];
                }
    }
    __syncthreads();
    if (wv >= 4) {
#pragma unroll
        for (int mt = 0; mt < 2; ++mt)
#pragma unroll
            for (int nt = 0; nt < 4; ++nt)
#pragma unroll
                for (int r = 0; r < 4; ++r) {
                    int tok = 16 * mt + q * 4 + r;
                    int e   = 16 * nt + r16;
                    red[wv - 4][tok][swz_e(tok, e)] += acc[mt][nt][r];
                }
    }
    __syncthreads();

    // ---- epilogue: 4 tokens/wave on lanes 0..3 (32 tokens total)
    if (lane < 4) {
        const int tk = wv * 4 + lane;
        const int t  = tok0 + tk;
        float lg[NEXP];
#pragma unroll
        for (int e = 0; e < NEXP; ++e) {
            int es = swz_e(tk, e);
            lg[e] = ((red[0][tk][es] + red[1][tk][es]) +
                     (red[2][tk][es] + red[3][tk][es])) + Bg[e];
        }
        float* outL = out + (size_t)t * NEXP;
#pragma unroll
        for (int e = 0; e < NEXP; e += 4) {
            float4 v = make_float4(lg[e], lg[e+1], lg[e+2], lg[e+3]);
            *(float4*)(outL + e) = v;
        }
        float mx = lg[0];
#pragma unroll
        for (int e = 1; e < NEXP; ++e) mx = fmaxf(mx, lg[e]);
        float S = 0.f;
#pragma unroll
        for (int e = 0; e < NEXP; ++e) { lg[e] = expf(lg[e] - mx); S += lg[e]; }
#pragma unroll
        for (int e = 0; e < NEXP; ++e) lg[e] = lg[e] / S;

        float v1 = lg[0]; int i1 = 0;
        float v2 = -1.0f; int i2 = 0;
#pragma unroll
        for (int e = 1; e < NEXP; ++e) {
            float rv = lg[e];
            bool g1 = rv > v1;
            bool g2 = rv > v2;
            float nv2 = g1 ? v1 : (g2 ? rv : v2);
            int   ni2 = g1 ? i1 : (g2 ? e  : i2);
            v2 = nv2; i2 = ni2;
            v1 = g1 ? rv : v1;
            i1 = g1 ? e  : i1;
        }
        float den = v1 + v2;
        float w1 = v1 / den, w2 = v2 / den;

        float* outW = out + (size_t)T_TOK * NEXP;
        float* outS = outW + (size_t)T_TOK * 2;
        float* outM = outS + (size_t)T_TOK * 2;
        outW[2*t+0] = w1;        outW[2*t+1] = w2;
        outS[2*t+0] = (float)i1; outS[2*t+1] = (float)i2;

        float* mrow = outM + (size_t)t * 2 * NEXP;
#pragma unroll
        for (int e = 0; e < NEXP; e += 4) {
            float4 a = make_float4(e+0==i1?1.f:0.f, e+1==i1?1.f:0.f,
                                   e+2==i1?1.f:0.f, e+3==i1?1.f:0.f);
            *(float4*)(mrow + e) = a;
            float4 b = make_float4(e+0==i2?1.f:0.f, e+1==i2?1.f:0.f,
                                   e+2==i2?1.f:0.f, e+3==i2?1.f:0.f);
            *(float4*)(mrow + NEXP + e) = b;
        }
    }
}

extern "C" void kernel_launch(void* const* d_in, const int* in_sizes, int n_in,
                              void* d_out, int out_size, void* d_ws, size_t ws_size,
                              hipStream_t stream)
{
    const float* X = (const float*)d_in[0];
    const float* W = (const float*)d_in[1];
    const float* B = (const float*)d_in[2];
    float* out     = (float*)d_out;
    unsigned short* ws = (unsigned short*)d_ws;   // needs 3*131072*2 = 768 KiB

    // pass 1: split W (64x2048 fp32) into bf16 h/m/l planes
    hipLaunchKernelGGL(split_w_kernel, dim3(128), dim3(256), 0, stream, W, ws);
    // pass 2: router GEMM + softmax/top-2 epilogue
    hipLaunchKernelGGL(moe_router_mfma, dim3(T_TOK / TPB), dim3(512), 0, stream,
                       X, ws, B, out);
}

// Round 6
// 242.931 us; speedup vs baseline: 2.0893x; 1.0726x over previous
//
#include <hip/hip_runtime.h>
#include <math.h>

constexpr int T_TOK = 16384;
constexpr int HDIM  = 2048;
constexpr int NEXP  = 64;
constexpr int TPB   = 64;          // tokens per block
constexpr int NKS   = 32;          // k-steps of 32 per k-half (2 halves x 1024)
constexpr int KHS   = 32 * 6144;   // ushort stride between kh regions in Ws

typedef __attribute__((ext_vector_type(8))) short v8s;   // 8 bf16
typedef __attribute__((ext_vector_type(4))) float v4f;   // 4 fp32

#define MFMA_BF16 __builtin_amdgcn_mfma_f32_16x16x32_bf16

// Truncation split: x = h + m + l exactly to ~24 mantissa bits.
static __device__ __forceinline__ void split3(float x, unsigned short& h,
                                              unsigned short& m, unsigned short& l)
{
    unsigned u0 = __float_as_uint(x);
    h = (unsigned short)(u0 >> 16);
    float r1 = x - __uint_as_float(u0 & 0xFFFF0000u);
    unsigned u1 = __float_as_uint(r1);
    m = (unsigned short)(u1 >> 16);
    float r2 = r1 - __uint_as_float(u1 & 0xFFFF0000u);
    l = (unsigned short)(__float_as_uint(r2) >> 16);
}

static __device__ __forceinline__ void frag3(const float4& x0, const float4& x1,
                                             v8s& h, v8s& m, v8s& l)
{
    unsigned short sh, sm, sl;
    split3(x0.x, sh, sm, sl); h[0]=(short)sh; m[0]=(short)sm; l[0]=(short)sl;
    split3(x0.y, sh, sm, sl); h[1]=(short)sh; m[1]=(short)sm; l[1]=(short)sl;
    split3(x0.z, sh, sm, sl); h[2]=(short)sh; m[2]=(short)sm; l[2]=(short)sl;
    split3(x0.w, sh, sm, sl); h[3]=(short)sh; m[3]=(short)sm; l[3]=(short)sl;
    split3(x1.x, sh, sm, sl); h[4]=(short)sh; m[4]=(short)sm; l[4]=(short)sl;
    split3(x1.y, sh, sm, sl); h[5]=(short)sh; m[5]=(short)sm; l[5]=(short)sl;
    split3(x1.z, sh, sm, sl); h[6]=(short)sh; m[6]=(short)sm; l[6]=(short)sl;
    split3(x1.w, sh, sm, sl); h[7]=(short)sh; m[7]=(short)sm; l[7]=(short)sl;
}

// ---- pass 1: W -> bf16 h/m/l planes laid out in exact MFMA B-fragment order.
// Ws[kh][ks][plane][nt][lane][8]:  element = W[e = nt*16 + (lane&15)]
//                                           [k = kh*1024 + ks*32 + (lane>>4)*8 + j]
__global__ __launch_bounds__(256)
void split_w_frag(const float* __restrict__ W, unsigned short* __restrict__ ws)
{
    int idx  = blockIdx.x * 256 + threadIdx.x;   // 0..16383
    int lane = idx & 63;
    int nt   = (idx >> 6) & 3;
    int ks   = (idx >> 8) & 31;
    int kh   = idx >> 13;
    int e    = nt * 16 + (lane & 15);
    int k0   = kh * 1024 + ks * 32 + (lane >> 4) * 8;
    const float* p = W + (size_t)e * HDIM + k0;
    float4 x0 = *(const float4*)p;
    float4 x1 = *(const float4*)(p + 4);
    v8s h, m, l;
    frag3(x0, x1, h, m, l);
    size_t bks = (size_t)(kh * 32 + ks) * 6144;
    *(v8s*)(ws + bks + (0 * 4 + nt) * 512 + lane * 8) = h;
    *(v8s*)(ws + bks + (1 * 4 + nt) * 512 + lane * 8) = m;
    *(v8s*)(ws + bks + (2 * 4 + nt) * 512 + lane * 8) = l;
}

// ---- pass 2: router. 256 blocks x 512 thr; waves = (mt2, nt2, kh).
__global__ __launch_bounds__(512, 2)
void moe_router_mfma(const float* __restrict__ X,
                     const unsigned short* __restrict__ Ws,
                     const float* __restrict__ Bg,
                     float* __restrict__ out)
{
    // 48 KB: double-buffered B stage (24 chunks x 1 KB each).
    __shared__ alignas(16) unsigned short Bld[2][24 * 512];
    // reduction buffer aliases Bld[0] (dead after the k-loop; 17.4 KB <= 24 KB)
    float* red = (float*)&Bld[0][0];

    const int tid  = threadIdx.x;
    const int lane = tid & 63;
    const int wv   = __builtin_amdgcn_readfirstlane(tid >> 6);
    const int r16  = lane & 15;
    const int q    = lane >> 4;
    const int mt2  = wv & 1;
    const int nt2  = (wv >> 1) & 1;
    const int kh   = wv >> 2;
    const int tok0 = blockIdx.x * TPB;

    // B staging: wave stages chunks 3*wv .. 3*wv+2 every ks
    const unsigned short* pWc[3];
#pragma unroll
    for (int cc = 0; cc < 3; ++cc) {
        int c = 3 * wv + cc;
        pWc[cc] = Ws + (size_t)(c / 12) * KHS + (c % 12) * 512 + lane * 8;
    }

    // A source: X[tok0 + 32*mt2 + 16*i + r16][kh*1024 + ks*32 + q*8 ..]
    const float* pA = X + (size_t)(tok0 + 32 * mt2 + r16) * HDIM + kh * 1024 + q * 8;

    v4f acc[2][2];
#pragma unroll
    for (int i = 0; i < 2; ++i)
#pragma unroll
        for (int t = 0; t < 2; ++t)
            acc[i][t] = (v4f){0.f, 0.f, 0.f, 0.f};

    // prologue: stage B(0), load A(0)
    int4 brn[3];
#pragma unroll
    for (int cc = 0; cc < 3; ++cc) brn[cc] = *(const int4*)(pWc[cc]);
#pragma unroll
    for (int cc = 0; cc < 3; ++cc)
        *(int4*)&Bld[0][(3 * wv + cc) * 512 + lane * 8] = brn[cc];
    float4 a0c[2], a1c[2], a0n[2], a1n[2];
#pragma unroll
    for (int i = 0; i < 2; ++i) {
        a0c[i] = *(const float4*)(pA + (size_t)i * 16 * HDIM);
        a1c[i] = *(const float4*)(pA + (size_t)i * 16 * HDIM + 4);
    }
    __syncthreads();

#pragma unroll 2
    for (int ks = 0; ks < NKS; ++ks) {
        const int cur = ks & 1, nxt = cur ^ 1;
        const int ksn = (ks + 1 < NKS) ? ks + 1 : ks;

        // issue next-step global loads first (latency covered by compute below)
#pragma unroll
        for (int cc = 0; cc < 3; ++cc)
            brn[cc] = *(const int4*)(pWc[cc] + (size_t)ksn * 6144);
#pragma unroll
        for (int i = 0; i < 2; ++i) {
            a0n[i] = *(const float4*)(pA + (size_t)i * 16 * HDIM + ksn * 32);
            a1n[i] = *(const float4*)(pA + (size_t)i * 16 * HDIM + ksn * 32 + 4);
        }

        // compute on current buffers
        v8s Ah[2], Am[2], Al[2];
        frag3(a0c[0], a1c[0], Ah[0], Am[0], Al[0]);
        frag3(a0c[1], a1c[1], Ah[1], Am[1], Al[1]);
#pragma unroll
        for (int t = 0; t < 2; ++t) {
            const int ntl = 2 * nt2 + t;
            const unsigned short* bp = &Bld[cur][(kh * 12 + ntl) * 512 + lane * 8];
            v8s Bh = *(const v8s*)(bp);
            v8s Bm = *(const v8s*)(bp + 4 * 512);
            v8s Bl = *(const v8s*)(bp + 8 * 512);
#pragma unroll
            for (int i = 0; i < 2; ++i) {
                v4f a = acc[i][t];
                a = MFMA_BF16(Ah[i], Bh, a, 0, 0, 0);
                a = MFMA_BF16(Ah[i], Bm, a, 0, 0, 0);
                a = MFMA_BF16(Am[i], Bh, a, 0, 0, 0);
                a = MFMA_BF16(Ah[i], Bl, a, 0, 0, 0);
                a = MFMA_BF16(Al[i], Bh, a, 0, 0, 0);
                a = MFMA_BF16(Am[i], Bm, a, 0, 0, 0);
                acc[i][t] = a;
            }
        }

        // stage next B chunk into the other buffer; rotate A
        if (ks + 1 < NKS) {
#pragma unroll
            for (int cc = 0; cc < 3; ++cc)
                *(int4*)&Bld[nxt][(3 * wv + cc) * 512 + lane * 8] = brn[cc];
        }
#pragma unroll
        for (int i = 0; i < 2; ++i) { a0c[i] = a0n[i]; a1c[i] = a1n[i]; }
        __syncthreads();
    }

    // ---- cross-kh reduction into red[tok][68-pitch]
    if (kh == 0) {
#pragma unroll
        for (int i = 0; i < 2; ++i)
#pragma unroll
            for (int t = 0; t < 2; ++t)
#pragma unroll
                for (int r = 0; r < 4; ++r) {
                    int tok = 32 * mt2 + 16 * i + q * 4 + r;
                    int e   = (2 * nt2 + t) * 16 + r16;
                    red[tok * 68 + e] = acc[i][t][r];
                }
    }
    __syncthreads();
    if (kh == 1) {
#pragma unroll
        for (int i = 0; i < 2; ++i)
#pragma unroll
            for (int t = 0; t < 2; ++t)
#pragma unroll
                for (int r = 0; r < 4; ++r) {
                    int tok = 32 * mt2 + 16 * i + q * 4 + r;
                    int e   = (2 * nt2 + t) * 16 + r16;
                    red[tok * 68 + e] += acc[i][t][r];
                }
    }
    __syncthreads();

    // ---- epilogue: 8 tokens/wave on lanes 0..7
    if (lane < 8) {
        const int tk = wv * 8 + lane;
        const int t  = tok0 + tk;
        float lg[NEXP];
#pragma unroll
        for (int e = 0; e < NEXP; e += 4) {
            float4 v  = *(const float4*)&red[tk * 68 + e];
            float4 bb = *(const float4*)&Bg[e];
            lg[e+0] = v.x + bb.x; lg[e+1] = v.y + bb.y;
            lg[e+2] = v.z + bb.z; lg[e+3] = v.w + bb.w;
        }
        float* outL = out + (size_t)t * NEXP;
#pragma unroll
        for (int e = 0; e < NEXP; e += 4) {
            float4 v = make_float4(lg[e], lg[e+1], lg[e+2], lg[e+3]);
            *(float4*)(outL + e) = v;
        }
        float mx = lg[0];
#pragma unroll
        for (int e = 1; e < NEXP; ++e) mx = fmaxf(mx, lg[e]);
        float S = 0.f;
#pragma unroll
        for (int e = 0; e < NEXP; ++e) { lg[e] = expf(lg[e] - mx); S += lg[e]; }
#pragma unroll
        for (int e = 0; e < NEXP; ++e) lg[e] = lg[e] / S;

        float v1 = lg[0]; int i1 = 0;
        float v2 = -1.0f; int i2 = 0;
#pragma unroll
        for (int e = 1; e < NEXP; ++e) {
            float rv = lg[e];
            bool g1 = rv > v1;
            bool g2 = rv > v2;
            float nv2 = g1 ? v1 : (g2 ? rv : v2);
            int   ni2 = g1 ? i1 : (g2 ? e  : i2);
            v2 = nv2; i2 = ni2;
            v1 = g1 ? rv : v1;
            i1 = g1 ? e  : i1;
        }
        float den = v1 + v2;
        float w1 = v1 / den, w2 = v2 / den;

        float* outW = out + (size_t)T_TOK * NEXP;
        float* outS = outW + (size_t)T_TOK * 2;
        float* outM = outS + (size_t)T_TOK * 2;
        outW[2*t+0] = w1;        outW[2*t+1] = w2;
        outS[2*t+0] = (float)i1; outS[2*t+1] = (float)i2;

        float* mrow = outM + (size_t)t * 2 * NEXP;
#pragma unroll
        for (int e = 0; e < NEXP; e += 4) {
            float4 a = make_float4(e+0==i1?1.f:0.f, e+1==i1?1.f:0.f,
                                   e+2==i1?1.f:0.f, e+3==i1?1.f:0.f);
            *(float4*)(mrow + e) = a;
            float4 b = make_float4(e+0==i2?1.f:0.f, e+1==i2?1.f:0.f,
                                   e+2==i2?1.f:0.f, e+3==i2?1.f:0.f);
            *(float4*)(mrow + NEXP + e) = b;
        }
    }
}

extern "C" void kernel_launch(void* const* d_in, const int* in_sizes, int n_in,
                              void* d_out, int out_size, void* d_ws, size_t ws_size,
                              hipStream_t stream)
{
    const float* X = (const float*)d_in[0];
    const float* W = (const float*)d_in[1];
    const float* B = (const float*)d_in[2];
    float* out     = (float*)d_out;
    unsigned short* ws = (unsigned short*)d_ws;   // 768 KiB

    hipLaunchKernelGGL(split_w_frag, dim3(64), dim3(256), 0, stream, W, ws);
    hipLaunchKernelGGL(moe_router_mfma, dim3(T_TOK / TPB), dim3(512), 0, stream,
                       X, ws, B, out);
}